// Round 1
// baseline (477.012 us; speedup 1.0000x reference)
//
#include <hip/hip_runtime.h>
#include <hip/hip_bf16.h>
#include <stdint.h>

#define B_  4
#define T_  300
#define U_  60
#define H_  1024
#define V_  1000
#define M_TOT (B_*T_*U_)   // 72000
#define KDIM 1024

typedef __attribute__((ext_vector_type(8))) short short8;
typedef __attribute__((ext_vector_type(4))) float f32x4;
typedef __attribute__((ext_vector_type(4))) int int4v;

__device__ __forceinline__ short f2bf(float f) {
    union { float f; uint32_t u; } c; c.f = f;
    uint32_t u = c.u;
    uint32_t r = (u + 0x7FFFu + ((u >> 16) & 1u)) >> 16;
    return (short)r;
}

__device__ __forceinline__ float fast_tanh(float x) {
    // tanh(x) = 1 - 2/(exp(2x)+1); robust at +-inf of exp
    float e = __expf(2.0f * x);
    float r = __builtin_amdgcn_rcpf(e + 1.0f);
    return 1.0f - 2.0f * r;
}

// in: fp32 [R][C] row-major  ->  out: bf16 [CP][R] (CP = gridDim.x*64), zero-padded for c>=C
__global__ void transpose_cvt(const float* __restrict__ in, short* __restrict__ out,
                              int R, int C) {
    __shared__ float tile[64][65];
    const int tx = threadIdx.x & 63, ty = threadIdx.x >> 6;
    const int r0 = blockIdx.y * 64, c0 = blockIdx.x * 64;
#pragma unroll
    for (int i = 0; i < 16; ++i) {
        int r = r0 + i * 4 + ty, c = c0 + tx;
        float v = 0.f;
        if (r < R && c < C) v = in[(long)r * C + c];
        tile[i * 4 + ty][tx] = v;
    }
    __syncthreads();
#pragma unroll
    for (int i = 0; i < 16; ++i) {
        int oc = c0 + i * 4 + ty;   // transposed row
        int orr = r0 + tx;
        out[(long)oc * R + orr] = f2bf(tile[tx][i * 4 + ty]);
    }
}

// P[M][1024] = bf16(X[M][512]) @ W1t[k_off:k_off+512]^T (+ b1)
__global__ __launch_bounds__(256, 2) void proj_gemm(
        const float* __restrict__ X, int M, int k_off,
        const short* __restrict__ Wt,   // [1024 h][1024 k] bf16
        const float* __restrict__ b1,   // nullable
        float* __restrict__ P)
{
    __shared__ short As[64 * 64];       // [row][k] bf16, XOR-swizzled
    const int tid = threadIdx.x;
    const int lane = tid & 63;
    const int w = tid >> 6;             // 4 waves
    const int wm = w >> 1, wn = w & 1;  // 2x2 wave grid, 32x32 tiles
    const int m0 = blockIdx.x * 64, n0 = blockIdx.y * 64;

    f32x4 acc[2][2] = {};
    for (int k0 = 0; k0 < 512; k0 += 64) {
        // stage A slice: 64 rows x 64 k, 2 chunks of 8 elems per thread
#pragma unroll
        for (int c = 0; c < 2; ++c) {
            int lin = tid + 256 * c;
            int row = lin >> 3, k8 = lin & 7;
            int m = m0 + row;
            short vals[8];
            if (m < M) {
                const float* xp = X + (long)m * 512 + k0 + k8 * 8;
#pragma unroll
                for (int j = 0; j < 8; ++j) vals[j] = f2bf(xp[j]);
            } else {
#pragma unroll
                for (int j = 0; j < 8; ++j) vals[j] = 0;
            }
            int byte = row * 128 + k8 * 16;
            byte ^= (row & 7) << 4;
            *(int4v*)((char*)As + byte) = *(const int4v*)vals;
        }
        __syncthreads();
#pragma unroll
        for (int ks = 0; ks < 2; ++ks) {
            short8 af[2];
#pragma unroll
            for (int mf = 0; mf < 2; ++mf) {
                int row = wm * 32 + mf * 16 + (lane & 15);
                int byte = row * 128 + ks * 64 + (lane >> 4) * 16;
                byte ^= (row & 7) << 4;
                af[mf] = *(const short8*)((char*)As + byte);
            }
#pragma unroll
            for (int nf = 0; nf < 2; ++nf) {
                int h = n0 + wn * 32 + nf * 16 + (lane & 15);
                const short* bp = Wt + (long)h * 1024 + k_off + k0 + ks * 32 + (lane >> 4) * 8;
                short8 bfv = *(const short8*)bp;
#pragma unroll
                for (int mf = 0; mf < 2; ++mf)
                    acc[mf][nf] = __builtin_amdgcn_mfma_f32_16x16x32_bf16(af[mf], bfv, acc[mf][nf], 0, 0, 0);
            }
        }
        __syncthreads();
    }
#pragma unroll
    for (int mf = 0; mf < 2; ++mf)
#pragma unroll
        for (int nf = 0; nf < 2; ++nf) {
            int h = n0 + wn * 32 + nf * 16 + (lane & 15);
            float bb = b1 ? b1[h] : 0.f;
#pragma unroll
            for (int j = 0; j < 4; ++j) {
                int m = m0 + wm * 32 + mf * 16 + (lane >> 4) * 4 + j;
                if (m < M) P[(long)m * 1024 + h] = acc[mf][nf][j] + bb;
            }
        }
}

// out[m][v] = tanh(encP[bt] + decP[bu]) @ W2t^T + b2   (A generated on the fly)
__global__ __launch_bounds__(512, 2) void joint_gemm(
        const float* __restrict__ encP,  // [1200][1024] fp32
        const float* __restrict__ decP,  // [240][1024] fp32 (b1 pre-added)
        const short* __restrict__ W2t,   // [1024 n][1024 k] bf16 (n>=1000 zero)
        const float* __restrict__ b2,
        float* __restrict__ out)
{
    __shared__ short As[64 * 64];        // [row][k] bf16, XOR-swizzled
    const int tid = threadIdx.x;
    const int lane = tid & 63;
    const int w = tid >> 6;              // 8 waves, wave tile 64x64 (n = w*64)
    const int m0 = blockIdx.x * 64;
    const int n0 = blockIdx.y * 512;

    // each thread owns one A row (8 k-elems per K-step)
    const int arow = tid >> 3;
    const int k8 = tid & 7;
    const int am = m0 + arow;
    const int bt = am / U_;
    const int u = am - bt * U_;
    const int bb_ = am / (T_ * U_);
    const float* eptr = encP + (long)bt * 1024 + k8 * 8;
    const float* dptr = decP + (long)(bb_ * U_ + u) * 1024 + k8 * 8;

    f32x4 acc[4][4] = {};
    const short* bbase[4];
#pragma unroll
    for (int nf = 0; nf < 4; ++nf) {
        int n = n0 + w * 64 + nf * 16 + (lane & 15);
        bbase[nf] = W2t + (long)n * 1024 + (lane >> 4) * 8;
    }

    for (int k0 = 0; k0 < KDIM; k0 += 64) {
        // generate A slice: hidden = tanh(enc + dec(+b1 already))
        {
            const float* e = eptr + k0;
            const float* d = dptr + k0;
            short vals[8];
#pragma unroll
            for (int j = 0; j < 8; ++j) {
                float x = e[j] + d[j];
                vals[j] = f2bf(fast_tanh(x));
            }
            int byte = arow * 128 + k8 * 16;
            byte ^= (arow & 7) << 4;
            *(int4v*)((char*)As + byte) = *(const int4v*)vals;
        }
        __syncthreads();
#pragma unroll
        for (int ks = 0; ks < 2; ++ks) {
            short8 af[4];
#pragma unroll
            for (int mf = 0; mf < 4; ++mf) {
                int row = mf * 16 + (lane & 15);
                int byte = row * 128 + ks * 64 + (lane >> 4) * 16;
                byte ^= (row & 7) << 4;
                af[mf] = *(const short8*)((char*)As + byte);
            }
#pragma unroll
            for (int nf = 0; nf < 4; ++nf) {
                short8 bfv = *(const short8*)(bbase[nf] + k0 + ks * 32);
#pragma unroll
                for (int mf = 0; mf < 4; ++mf)
                    acc[mf][nf] = __builtin_amdgcn_mfma_f32_16x16x32_bf16(af[mf], bfv, acc[mf][nf], 0, 0, 0);
            }
        }
        __syncthreads();
    }

    // epilogue: + b2, store fp32
#pragma unroll
    for (int nf = 0; nf < 4; ++nf) {
        int n = n0 + w * 64 + nf * 16 + (lane & 15);
        float bv = (n < V_) ? b2[n] : 0.f;
#pragma unroll
        for (int mf = 0; mf < 4; ++mf) {
#pragma unroll
            for (int j = 0; j < 4; ++j) {
                int m = m0 + mf * 16 + (lane >> 4) * 4 + j;
                if (n < V_ && m < M_TOT)
                    out[(long)m * V_ + n] = acc[mf][nf][j] + bv;
            }
        }
    }
}

extern "C" void kernel_launch(void* const* d_in, const int* in_sizes, int n_in,
                              void* d_out, int out_size, void* d_ws, size_t ws_size,
                              hipStream_t stream) {
    const float* enc = (const float*)d_in[0];   // [4][300][512]
    const float* dec = (const float*)d_in[1];   // [4][60][512]
    const float* W1  = (const float*)d_in[2];   // [1024][1024]
    const float* b1  = (const float*)d_in[3];   // [1024]
    const float* W2  = (const float*)d_in[4];   // [1024][1000]
    const float* b2  = (const float*)d_in[5];   // [1000]
    float* out = (float*)d_out;

    char* ws = (char*)d_ws;
    short* W1t  = (short*)ws;                         // 1024*1024*2 = 2 MB  [h][k]
    short* W2t  = (short*)(ws + (2 << 20));           // 2 MB                [n][k]
    float* encP = (float*)(ws + (4 << 20));           // 1200*1024*4 = 4.69 MB
    float* decP = (float*)(ws + (4 << 20) + 1200 * 1024 * 4); // 240*1024*4

    // prep: transpose+convert weights to bf16 [n][k]
    transpose_cvt<<<dim3(16, 16), 256, 0, stream>>>(W1, W1t, 1024, 1024);
    transpose_cvt<<<dim3(16, 16), 256, 0, stream>>>(W2, W2t, 1024, 1000);

    // projections (enc: W1 rows 0..511; dec: rows 512..1023, +b1 folded in)
    proj_gemm<<<dim3(19, 16), 256, 0, stream>>>(enc, 1200, 0,   W1t, nullptr, encP);
    proj_gemm<<<dim3(4, 16),  256, 0, stream>>>(dec, 240,  512, W1t, b1,      decP);

    // fused tanh + GEMM  (M=72000 = 1125*64, N covered by 2 tiles of 512)
    joint_gemm<<<dim3(1125, 2), 512, 0, stream>>>(encP, decP, W2t, b2, out);
}

// Round 2
// 435.518 us; speedup vs baseline: 1.0953x; 1.0953x over previous
//
#include <hip/hip_runtime.h>
#include <hip/hip_bf16.h>
#include <stdint.h>

#define B_  4
#define T_  300
#define U_  60
#define H_  1024
#define V_  1000
#define M_TOT (B_*T_*U_)   // 72000
#define KDIM 1024

typedef __attribute__((ext_vector_type(8))) short short8;
typedef __attribute__((ext_vector_type(4))) float f32x4;
typedef __attribute__((ext_vector_type(4))) int int4v;

__device__ __forceinline__ short f2bf(float f) {
    union { float f; uint32_t u; } c; c.f = f;
    uint32_t u = c.u;
    uint32_t r = (u + 0x7FFFu + ((u >> 16) & 1u)) >> 16;
    return (short)r;
}

__device__ __forceinline__ float fast_tanh(float x) {
    float e = __expf(2.0f * x);
    float r = __builtin_amdgcn_rcpf(e + 1.0f);
    return 1.0f - 2.0f * r;
}

// in: fp32 [R][C] row-major  ->  out: bf16 [CP][R], zero-padded for c>=C
__global__ void transpose_cvt(const float* __restrict__ in, short* __restrict__ out,
                              int R, int C) {
    __shared__ float tile[64][65];
    const int tx = threadIdx.x & 63, ty = threadIdx.x >> 6;
    const int r0 = blockIdx.y * 64, c0 = blockIdx.x * 64;
#pragma unroll
    for (int i = 0; i < 16; ++i) {
        int r = r0 + i * 4 + ty, c = c0 + tx;
        float v = 0.f;
        if (r < R && c < C) v = in[(long)r * C + c];
        tile[i * 4 + ty][tx] = v;
    }
    __syncthreads();
#pragma unroll
    for (int i = 0; i < 16; ++i) {
        int oc = c0 + i * 4 + ty;
        int orr = r0 + tx;
        out[(long)oc * R + orr] = f2bf(tile[tx][i * 4 + ty]);
    }
}

// P[M][1024] = bf16(X[M][512]) @ W1t[k_off:k_off+512]^T (+ b1)
__global__ __launch_bounds__(256, 2) void proj_gemm(
        const float* __restrict__ X, int M, int k_off,
        const short* __restrict__ Wt,
        const float* __restrict__ b1,
        float* __restrict__ P)
{
    __shared__ short As[64 * 64];
    const int tid = threadIdx.x;
    const int lane = tid & 63;
    const int w = tid >> 6;
    const int wm = w >> 1, wn = w & 1;
    const int m0 = blockIdx.x * 64, n0 = blockIdx.y * 64;

    f32x4 acc[2][2] = {};
    for (int k0 = 0; k0 < 512; k0 += 64) {
#pragma unroll
        for (int c = 0; c < 2; ++c) {
            int lin = tid + 256 * c;
            int row = lin >> 3, k8 = lin & 7;
            int m = m0 + row;
            short vals[8];
            if (m < M) {
                const float* xp = X + (long)m * 512 + k0 + k8 * 8;
#pragma unroll
                for (int j = 0; j < 8; ++j) vals[j] = f2bf(xp[j]);
            } else {
#pragma unroll
                for (int j = 0; j < 8; ++j) vals[j] = 0;
            }
            int byte = row * 128 + k8 * 16;
            byte ^= (row & 7) << 4;
            *(int4v*)((char*)As + byte) = *(const int4v*)vals;
        }
        __syncthreads();
#pragma unroll
        for (int ks = 0; ks < 2; ++ks) {
            short8 af[2];
#pragma unroll
            for (int mf = 0; mf < 2; ++mf) {
                int row = wm * 32 + mf * 16 + (lane & 15);
                int byte = row * 128 + ks * 64 + (lane >> 4) * 16;
                byte ^= (row & 7) << 4;
                af[mf] = *(const short8*)((char*)As + byte);
            }
#pragma unroll
            for (int nf = 0; nf < 2; ++nf) {
                int h = n0 + wn * 32 + nf * 16 + (lane & 15);
                const short* bp = Wt + (long)h * 1024 + k_off + k0 + ks * 32 + (lane >> 4) * 8;
                short8 bfv = *(const short8*)bp;
#pragma unroll
                for (int mf = 0; mf < 2; ++mf)
                    acc[mf][nf] = __builtin_amdgcn_mfma_f32_16x16x32_bf16(af[mf], bfv, acc[mf][nf], 0, 0, 0);
            }
        }
        __syncthreads();
    }
#pragma unroll
    for (int mf = 0; mf < 2; ++mf)
#pragma unroll
        for (int nf = 0; nf < 2; ++nf) {
            int h = n0 + wn * 32 + nf * 16 + (lane & 15);
            float bb = b1 ? b1[h] : 0.f;
#pragma unroll
            for (int j = 0; j < 4; ++j) {
                int m = m0 + wm * 32 + mf * 16 + (lane >> 4) * 4 + j;
                if (m < M) P[(long)m * 1024 + h] = acc[mf][nf][j] + bb;
            }
        }
}

__device__ __forceinline__ void gen_slice(char* dst_byte,
        f32x4 e0, f32x4 e1, f32x4 d0, f32x4 d1) {
    short vals[8];
#pragma unroll
    for (int j = 0; j < 4; ++j) vals[j]     = f2bf(fast_tanh(e0[j] + d0[j]));
#pragma unroll
    for (int j = 0; j < 4; ++j) vals[4 + j] = f2bf(fast_tanh(e1[j] + d1[j]));
    *(int4v*)dst_byte = *(const int4v*)vals;
}

// out[m][v] = tanh(encP[bt] + decP[bu]) @ W2t^T + b2, A generated on the fly.
// Double-buffered A slice + raw s_barrier (lgkmcnt-only drain): B loads and
// enc/dec prefetch stay in flight across barriers.
__global__ __launch_bounds__(512, 3) void joint_gemm(
        const float* __restrict__ encP,  // [1200][1024] fp32
        const float* __restrict__ decP,  // [240][1024] fp32 (b1 pre-added)
        const short* __restrict__ W2t,   // [1024 n][1024 k] bf16 (n>=1000 zero)
        const float* __restrict__ b2,
        float* __restrict__ out)
{
    __shared__ short As[2][64 * 64];     // double-buffered, XOR-swizzled
    const int tid = threadIdx.x;
    const int lane = tid & 63;
    const int w = tid >> 6;              // 8 waves, wave n-tile 64
    const int m0 = blockIdx.x * 64;
    const int n0 = blockIdx.y * 512;

    // per-thread A-row assignment (8 k-floats per slice)
    const int arow = tid >> 3;
    const int k8 = tid & 7;
    const int am = m0 + arow;            // M_TOT % 64 == 0 -> always valid
    const int bt = am / U_;
    const int u = am - bt * U_;
    const int bidx = am / (T_ * U_);
    const float* eptr = encP + (long)bt * 1024 + k8 * 8;
    const float* dptr = decP + (long)(bidx * U_ + u) * 1024 + k8 * 8;
    const int wbyte = (arow * 128 + k8 * 16) ^ ((arow & 7) << 4);

    f32x4 acc[4][4] = {};
    const short* bbase[4];
#pragma unroll
    for (int nf = 0; nf < 4; ++nf) {
        int n = n0 + w * 64 + nf * 16 + (lane & 15);
        bbase[nf] = W2t + (long)n * 1024 + (lane >> 4) * 8;
    }

    // ---- prologue: slice 0 generate+write, issue slice-1 loads ----
    f32x4 e0 = *(const f32x4*)(eptr);
    f32x4 e1 = *(const f32x4*)(eptr + 4);
    f32x4 d0 = *(const f32x4*)(dptr);
    f32x4 d1 = *(const f32x4*)(dptr + 4);
    gen_slice((char*)&As[0][0] + wbyte, e0, e1, d0, d1);
    e0 = *(const f32x4*)(eptr + 64);
    e1 = *(const f32x4*)(eptr + 68);
    d0 = *(const f32x4*)(dptr + 64);
    d1 = *(const f32x4*)(dptr + 68);
    asm volatile("s_waitcnt lgkmcnt(0)" ::: "memory");
    __builtin_amdgcn_s_barrier();

    int cur = 0;
    for (int t = 0; t < 16; ++t) {
        const int k0 = t * 64;
        // 1) issue B-fragment loads (L2-resident W2t) — longest latency first
        short8 bfr[2][4];
#pragma unroll
        for (int ks = 0; ks < 2; ++ks)
#pragma unroll
            for (int nf = 0; nf < 4; ++nf)
                bfr[ks][nf] = *(const short8*)(bbase[nf] + k0 + ks * 32);
        // 2) A-fragment ds_reads from current buffer
        const char* rb = (const char*)&As[cur][0];
        short8 af[2][4];
#pragma unroll
        for (int ks = 0; ks < 2; ++ks)
#pragma unroll
            for (int mf = 0; mf < 4; ++mf) {
                int row = mf * 16 + (lane & 15);
                int byte = (row * 128 + ks * 64 + (lane >> 4) * 16) ^ ((row & 7) << 4);
                af[ks][mf] = *(const short8*)(rb + byte);
            }
        // 3) generate next slice into other buffer (VALU covers load latency)
        if (t < 15) {
            gen_slice((char*)&As[cur ^ 1][0] + wbyte, e0, e1, d0, d1);
            if (t < 14) {
                e0 = *(const f32x4*)(eptr + k0 + 128);
                e1 = *(const f32x4*)(eptr + k0 + 132);
                d0 = *(const f32x4*)(dptr + k0 + 128);
                d1 = *(const f32x4*)(dptr + k0 + 132);
            }
        }
        // 4) MFMA block
#pragma unroll
        for (int ks = 0; ks < 2; ++ks)
#pragma unroll
            for (int nf = 0; nf < 4; ++nf)
#pragma unroll
                for (int mf = 0; mf < 4; ++mf)
                    acc[mf][nf] = __builtin_amdgcn_mfma_f32_16x16x32_bf16(
                        af[ks][mf], bfr[ks][nf], acc[mf][nf], 0, 0, 0);
        // 5) LDS-only barrier: no vmcnt drain, loads stay in flight
        if (t < 15) {
            asm volatile("s_waitcnt lgkmcnt(0)" ::: "memory");
            __builtin_amdgcn_s_barrier();
        }
        cur ^= 1;
    }

    // epilogue: + b2, store fp32
#pragma unroll
    for (int nf = 0; nf < 4; ++nf) {
        int n = n0 + w * 64 + nf * 16 + (lane & 15);
        float bv = (n < V_) ? b2[n] : 0.f;
#pragma unroll
        for (int mf = 0; mf < 4; ++mf) {
#pragma unroll
            for (int j = 0; j < 4; ++j) {
                int m = m0 + mf * 16 + (lane >> 4) * 4 + j;
                if (n < V_)
                    out[(long)m * V_ + n] = acc[mf][nf][j] + bv;
            }
        }
    }
}

extern "C" void kernel_launch(void* const* d_in, const int* in_sizes, int n_in,
                              void* d_out, int out_size, void* d_ws, size_t ws_size,
                              hipStream_t stream) {
    const float* enc = (const float*)d_in[0];
    const float* dec = (const float*)d_in[1];
    const float* W1  = (const float*)d_in[2];
    const float* b1  = (const float*)d_in[3];
    const float* W2  = (const float*)d_in[4];
    const float* b2  = (const float*)d_in[5];
    float* out = (float*)d_out;

    char* ws = (char*)d_ws;
    short* W1t  = (short*)ws;                                  // 2 MB [h][k]
    short* W2t  = (short*)(ws + (2 << 20));                    // 2 MB [n][k]
    float* encP = (float*)(ws + (4 << 20));                    // 4.69 MB
    float* decP = (float*)(ws + (4 << 20) + 1200 * 1024 * 4);  // 0.94 MB

    transpose_cvt<<<dim3(16, 16), 256, 0, stream>>>(W1, W1t, 1024, 1024);
    transpose_cvt<<<dim3(16, 16), 256, 0, stream>>>(W2, W2t, 1024, 1000);

    proj_gemm<<<dim3(19, 16), 256, 0, stream>>>(enc, 1200, 0,   W1t, nullptr, encP);
    proj_gemm<<<dim3(4, 16),  256, 0, stream>>>(dec, 240,  512, W1t, b1,      decP);

    joint_gemm<<<dim3(1125, 2), 512, 0, stream>>>(encP, decP, W2t, b2, out);
}

// Round 3
// 354.856 us; speedup vs baseline: 1.3442x; 1.2273x over previous
//
#include <hip/hip_runtime.h>
#include <hip/hip_bf16.h>
#include <stdint.h>

#define B_  4
#define T_  300
#define U_  60
#define H_  1024
#define V_  1000
#define M_TOT (B_*T_*U_)   // 72000
#define KDIM 1024
#define WK  1056           // padded W row stride (shorts): 2112B = 33*64B
#define PK  1040           // padded proj row stride (floats): 4160B = 65*64B

typedef __attribute__((ext_vector_type(8))) short short8;
typedef __attribute__((ext_vector_type(4))) float f32x4;
typedef __attribute__((ext_vector_type(4))) int int4v;

__device__ __forceinline__ short f2bf(float f) {
    union { float f; uint32_t u; } c; c.f = f;
    uint32_t u = c.u;
    uint32_t r = (u + 0x7FFFu + ((u >> 16) & 1u)) >> 16;
    return (short)r;
}

__device__ __forceinline__ float fast_tanh(float x) {
    float e = __expf(2.0f * x);
    float r = __builtin_amdgcn_rcpf(e + 1.0f);
    return 1.0f - 2.0f * r;
}

// in: fp32 [R][C] row-major -> out: bf16 [C rows][R cols] with row stride ostride
__global__ void transpose_cvt(const float* __restrict__ in, short* __restrict__ out,
                              int R, int C, int ostride) {
    __shared__ float tile[64][65];
    const int tx = threadIdx.x & 63, ty = threadIdx.x >> 6;
    const int r0 = blockIdx.y * 64, c0 = blockIdx.x * 64;
#pragma unroll
    for (int i = 0; i < 16; ++i) {
        int r = r0 + i * 4 + ty, c = c0 + tx;
        float v = 0.f;
        if (r < R && c < C) v = in[(long)r * C + c];
        tile[i * 4 + ty][tx] = v;
    }
    __syncthreads();
#pragma unroll
    for (int i = 0; i < 16; ++i) {
        int oc = c0 + i * 4 + ty;
        int orr = r0 + tx;
        out[(long)oc * ostride + orr] = f2bf(tile[tx][i * 4 + ty]);
    }
}

// P[M][PK] = bf16(X[M][512]) @ Wt[k_off:k_off+512]^T (+ b1)
__global__ __launch_bounds__(256, 2) void proj_gemm(
        const float* __restrict__ X, int M, int k_off,
        const short* __restrict__ Wt,   // [1024 h][WK] bf16
        const float* __restrict__ b1,
        float* __restrict__ P)
{
    __shared__ short As[64 * 64];
    const int tid = threadIdx.x;
    const int lane = tid & 63;
    const int w = tid >> 6;
    const int wm = w >> 1, wn = w & 1;
    const int m0 = blockIdx.x * 64, n0 = blockIdx.y * 64;

    f32x4 acc[2][2] = {};
    for (int k0 = 0; k0 < 512; k0 += 64) {
#pragma unroll
        for (int c = 0; c < 2; ++c) {
            int lin = tid + 256 * c;
            int row = lin >> 3, k8 = lin & 7;
            int m = m0 + row;
            short vals[8];
            if (m < M) {
                const float* xp = X + (long)m * 512 + k0 + k8 * 8;
#pragma unroll
                for (int j = 0; j < 8; ++j) vals[j] = f2bf(xp[j]);
            } else {
#pragma unroll
                for (int j = 0; j < 8; ++j) vals[j] = 0;
            }
            int byte = row * 128 + k8 * 16;
            byte ^= (row & 7) << 4;
            *(int4v*)((char*)As + byte) = *(const int4v*)vals;
        }
        __syncthreads();
#pragma unroll
        for (int ks = 0; ks < 2; ++ks) {
            short8 af[2];
#pragma unroll
            for (int mf = 0; mf < 2; ++mf) {
                int row = wm * 32 + mf * 16 + (lane & 15);
                int byte = row * 128 + ks * 64 + (lane >> 4) * 16;
                byte ^= (row & 7) << 4;
                af[mf] = *(const short8*)((char*)As + byte);
            }
#pragma unroll
            for (int nf = 0; nf < 2; ++nf) {
                int h = n0 + wn * 32 + nf * 16 + (lane & 15);
                const short* bp = Wt + (long)h * WK + k_off + k0 + ks * 32 + (lane >> 4) * 8;
                short8 bfv = *(const short8*)bp;
#pragma unroll
                for (int mf = 0; mf < 2; ++mf)
                    acc[mf][nf] = __builtin_amdgcn_mfma_f32_16x16x32_bf16(af[mf], bfv, acc[mf][nf], 0, 0, 0);
            }
        }
        __syncthreads();
    }
#pragma unroll
    for (int mf = 0; mf < 2; ++mf)
#pragma unroll
        for (int nf = 0; nf < 2; ++nf) {
            int h = n0 + wn * 32 + nf * 16 + (lane & 15);
            float bb = b1 ? b1[h] : 0.f;
#pragma unroll
            for (int j = 0; j < 4; ++j) {
                int m = m0 + wm * 32 + mf * 16 + (lane >> 4) * 4 + j;
                if (m < M) P[(long)m * PK + h] = acc[mf][nf][j] + bb;
            }
        }
}

__device__ __forceinline__ void gen_slice(char* dst_byte,
        f32x4 e0, f32x4 e1, f32x4 d0, f32x4 d1) {
    short vals[8];
#pragma unroll
    for (int j = 0; j < 4; ++j) vals[j]     = f2bf(fast_tanh(e0[j] + d0[j]));
#pragma unroll
    for (int j = 0; j < 4; ++j) vals[4 + j] = f2bf(fast_tanh(e1[j] + d1[j]));
    *(int4v*)dst_byte = *(const int4v*)vals;
}

// out[m][v] = tanh(encP[bt] + decP[bu]) @ W2t^T + b2, A generated on the fly.
// Padded strides (anti channel-conflict) + B register double-prefetch +
// double-buffered A slice + lgkm-only barriers.
__global__ __launch_bounds__(512, 2) void joint_gemm(
        const float* __restrict__ encP,  // [1200][PK] fp32
        const float* __restrict__ decP,  // [240][PK] fp32 (b1 pre-added)
        const short* __restrict__ W2t,   // [1024 n][WK] bf16
        const float* __restrict__ b2,
        float* __restrict__ out)
{
    __shared__ short As[2][64 * 64];
    const int tid = threadIdx.x;
    const int lane = tid & 63;
    const int w = tid >> 6;
    const int m0 = blockIdx.x * 64;
    const int n0 = blockIdx.y * 512;

    const int arow = tid >> 3;
    const int k8 = tid & 7;
    const int am = m0 + arow;
    const int bt = am / U_;
    const int u = am - bt * U_;
    const int bidx = am / (T_ * U_);
    const float* eptr = encP + (long)bt * PK + k8 * 8;
    const float* dptr = decP + (long)(bidx * U_ + u) * PK + k8 * 8;
    const int wbyte = (arow * 128 + k8 * 16) ^ ((arow & 7) << 4);

    f32x4 acc[4][4] = {};
    const short* bbase[4];
#pragma unroll
    for (int nf = 0; nf < 4; ++nf) {
        int n = n0 + w * 64 + nf * 16 + (lane & 15);
        bbase[nf] = W2t + (long)n * WK + (lane >> 4) * 8;
    }

#define LOADB(dst, k0_)                                            \
    _Pragma("unroll")                                              \
    for (int ks = 0; ks < 2; ++ks) {                               \
        _Pragma("unroll")                                          \
        for (int nf = 0; nf < 4; ++nf)                             \
            dst[ks][nf] = *(const short8*)(bbase[nf] + (k0_) + ks * 32); \
    }

#define BODY(t, bcur, bnext)                                                   \
    {                                                                          \
        const int k0 = (t) * 64;                                               \
        if ((t) + 1 < 16) { LOADB(bnext, k0 + 64); }                           \
        if ((t) < 15) {                                                        \
            gen_slice((char*)&As[((t) & 1) ^ 1][0] + wbyte, e0, e1, d0, d1);   \
            if ((t) < 14) {                                                    \
                e0 = *(const f32x4*)(eptr + k0 + 128);                         \
                e1 = *(const f32x4*)(eptr + k0 + 132);                         \
                d0 = *(const f32x4*)(dptr + k0 + 128);                         \
                d1 = *(const f32x4*)(dptr + k0 + 132);                         \
            }                                                                  \
        }                                                                      \
        const char* rb = (const char*)&As[(t) & 1][0];                         \
        _Pragma("unroll")                                                      \
        for (int ks = 0; ks < 2; ++ks) {                                       \
            short8 af[4];                                                      \
            _Pragma("unroll")                                                  \
            for (int mf = 0; mf < 4; ++mf) {                                   \
                int row = mf * 16 + (lane & 15);                               \
                int byte = (row * 128 + ks * 64 + (lane >> 4) * 16)            \
                           ^ ((row & 7) << 4);                                 \
                af[mf] = *(const short8*)(rb + byte);                          \
            }                                                                  \
            _Pragma("unroll")                                                  \
            for (int nf = 0; nf < 4; ++nf) {                                   \
                _Pragma("unroll")                                              \
                for (int mf = 0; mf < 4; ++mf)                                 \
                    acc[mf][nf] = __builtin_amdgcn_mfma_f32_16x16x32_bf16(     \
                        af[mf], bcur[ks][nf], acc[mf][nf], 0, 0, 0);           \
            }                                                                  \
        }                                                                      \
        if ((t) < 15) {                                                        \
            asm volatile("s_waitcnt lgkmcnt(0)" ::: "memory");                 \
            __builtin_amdgcn_s_barrier();                                      \
        }                                                                      \
    }

    // prologue: slice 0 gen+write, prefetch slice-1 e/d, first B tile
    f32x4 e0 = *(const f32x4*)(eptr);
    f32x4 e1 = *(const f32x4*)(eptr + 4);
    f32x4 d0 = *(const f32x4*)(dptr);
    f32x4 d1 = *(const f32x4*)(dptr + 4);
    gen_slice((char*)&As[0][0] + wbyte, e0, e1, d0, d1);
    e0 = *(const f32x4*)(eptr + 64);
    e1 = *(const f32x4*)(eptr + 68);
    d0 = *(const f32x4*)(dptr + 64);
    d1 = *(const f32x4*)(dptr + 68);
    short8 bA[2][4], bB[2][4];
    LOADB(bA, 0);
    asm volatile("s_waitcnt lgkmcnt(0)" ::: "memory");
    __builtin_amdgcn_s_barrier();

#pragma unroll 1
    for (int tt = 0; tt < 16; tt += 2) {
        BODY(tt, bA, bB);
        BODY(tt + 1, bB, bA);
    }

    // epilogue: + b2, store fp32
#pragma unroll
    for (int nf = 0; nf < 4; ++nf) {
        int n = n0 + w * 64 + nf * 16 + (lane & 15);
        float bv = (n < V_) ? b2[n] : 0.f;
#pragma unroll
        for (int mf = 0; mf < 4; ++mf) {
#pragma unroll
            for (int j = 0; j < 4; ++j) {
                int m = m0 + mf * 16 + (lane >> 4) * 4 + j;
                if (n < V_)
                    out[(long)m * V_ + n] = acc[mf][nf][j] + bv;
            }
        }
    }
#undef BODY
#undef LOADB
}

extern "C" void kernel_launch(void* const* d_in, const int* in_sizes, int n_in,
                              void* d_out, int out_size, void* d_ws, size_t ws_size,
                              hipStream_t stream) {
    const float* enc = (const float*)d_in[0];
    const float* dec = (const float*)d_in[1];
    const float* W1  = (const float*)d_in[2];
    const float* b1  = (const float*)d_in[3];
    const float* W2  = (const float*)d_in[4];
    const float* b2  = (const float*)d_in[5];
    float* out = (float*)d_out;

    char* ws = (char*)d_ws;
    size_t off = 0;
    short* W1t  = (short*)(ws + off); off += (size_t)1024 * WK * 2;      // 2.06 MB
    short* W2t  = (short*)(ws + off); off += (size_t)1024 * WK * 2;      // 2.06 MB
    float* encP = (float*)(ws + off); off += (size_t)1200 * PK * 4;      // 4.99 MB
    float* decP = (float*)(ws + off);                                    // 1.00 MB

    transpose_cvt<<<dim3(16, 16), 256, 0, stream>>>(W1, W1t, 1024, 1024, WK);
    transpose_cvt<<<dim3(16, 16), 256, 0, stream>>>(W2, W2t, 1024, 1000, WK);

    proj_gemm<<<dim3(19, 16), 256, 0, stream>>>(enc, 1200, 0,   W1t, nullptr, encP);
    proj_gemm<<<dim3(4, 16),  256, 0, stream>>>(dec, 240,  512, W1t, b1,      decP);

    joint_gemm<<<dim3(1125, 2), 512, 0, stream>>>(encP, decP, W2t, b2, out);
}